// Round 3
// baseline (492.741 us; speedup 1.0000x reference)
//
#include <hip/hip_runtime.h>

// WindowMultiHeadAttention: b=4, n=4096, d=1024, H=16, dk=64, WIN=64, nw=64.
// R3: keep R0's proven 128x128/BK32 single-buffer async-DMA GEMM structure,
// but stage the fp32 operand RAW into LDS (global_load_lds, 4 chunks/thread)
// and convert fp32->bf16 on the LDS->register fragment path (v_cvt_pk via
// compiler; no long-lived staging regs => no R2 load-sinking pathology).
// Eliminates all three 96-MB q/k/v cvt passes AND the Wo conversion:
// 9 launches -> 6.
//
// fp32 LDS tile uses an XOR granule swizzle: logical 16B-granule lg of row r
// is stored at physical lg^(r&7). Applied on the cp16 GLOBAL SOURCE address
// (DMA writes linearly) and on the fragment ds_read address (both-sides
// rule). Resulting read pattern has the identical 8-lanes-per-4-bank-group
// distribution as R0's proven bf16 b128 reads.
//
// Buffer plan:
//   d_out lower half : Xq (bf16)   -> clobbered by final fp32 C (Xq dead)
//   d_out upper half : Wb3 (Wq/Wk/Wv bf16, 6.3 MB) -> dead at final gemm
//   ws S1 : Xk ; S2 : Xv ; S3 : Xo
//   inputs never written; Wo consumed fp32 directly by the final GEMM.

typedef unsigned short u16;
typedef unsigned int u32;
typedef __bf16 bf16x8 __attribute__((ext_vector_type(8)));
typedef float f32x4 __attribute__((ext_vector_type(4)));
typedef u16 u16x8 __attribute__((ext_vector_type(8)));

__device__ __forceinline__ u16 f2bf(float f) {
  u32 u = __builtin_bit_cast(u32, f);
  u += 0x7fffu + ((u >> 16) & 1u);  // RNE
  return (u16)(u >> 16);
}

__device__ __forceinline__ u16x8 cvt2(float4 a, float4 b) {
  u16x8 r;
  r[0] = f2bf(a.x); r[1] = f2bf(a.y); r[2] = f2bf(a.z); r[3] = f2bf(a.w);
  r[4] = f2bf(b.x); r[5] = f2bf(b.y); r[6] = f2bf(b.z); r[7] = f2bf(b.w);
  return r;
}

// Wq/Wk/Wv fp32 -> bf16, 1M elems each.
__global__ __launch_bounds__(256) void cvtw3_kernel(
    const float* __restrict__ Wq, const float* __restrict__ Wk,
    const float* __restrict__ Wv, u16* __restrict__ dst) {
  const float* src = (blockIdx.z == 0) ? Wq : (blockIdx.z == 1) ? Wk : Wv;
  const size_t i = ((size_t)blockIdx.x * 256 + threadIdx.x) * 8;
  const float4 a = *(const float4*)(src + i);
  const float4 b = *(const float4*)(src + i + 4);
  *(u16x8*)(dst + (size_t)blockIdx.z * 1048576 + i) = cvt2(a, b);
}

__device__ __forceinline__ void cp16(const void* g, void* l) {
  // async global->LDS, 16B/lane; LDS dst = wave-uniform base + lane*16.
  __builtin_amdgcn_global_load_lds((const __attribute__((address_space(1))) void*)g,
                                   (__attribute__((address_space(3))) void*)l, 16, 0, 0);
}

// C[M,N] = A[M,K]*B[N,K]^T, M=16384, N=K=1024. 128x128 tile, BK=32, 4 waves
// 2x2, 1024 blocks. XCD swizzle: XCD x owns m-tiles [x*16,x*16+16), n fastest
// (R0-proven FETCH 26.5 MB). AF/BF: operand is fp32 in global -> raw fp32 LDS
// tile (16KB, swizzled) + fragment-path cvt. Else bf16 cp16 path (R0).
template <int AF, int BF, int CF>
__global__ __launch_bounds__(256, 2) void gemm_m_kernel(
    const void* __restrict__ Av, const void* __restrict__ Bv,
    void* __restrict__ Cv) {
  constexpr int N = 1024, K = 1024;
  __shared__ u16  lA16[AF ? 8 : 128 * 32];
  __shared__ float lA32[AF ? 128 * 32 : 8];
  __shared__ u16  lB16[BF ? 8 : 128 * 32];
  __shared__ float lB32[BF ? 128 * 32 : 8];
  const int tid = threadIdx.x;
  const int lane = tid & 63, w = tid >> 6;
  const int quad = lane >> 4, lr = lane & 15;
  const int lid = blockIdx.x;
  const int xcd = lid & 7, slot = lid >> 3;
  const int m0 = (xcd * 16 + (slot >> 3)) * 128;
  const int n0 = (slot & 7) * 128;
  const int wr = (w >> 1) * 64, wc = (w & 1) * 64;

  const u16* A16 = (const u16*)Av; const float* A32 = (const float*)Av;
  const u16* B16 = (const u16*)Bv; const float* B32 = (const float*)Bv;

  // bf16 staging: 512 x 16B slots, thread owns ch, ch+256 (row=ch>>2).
  const int ch1 = tid, ch2 = tid + 256;
  // fp32 staging: 1024 x 16B slots, thread owns s_i = tid+256i (row=s>>3,
  // phys granule gp=s&7, source granule gp^(row&7)).
  const u16 *Ag1 = nullptr, *Ag2 = nullptr, *Bg1 = nullptr, *Bg2 = nullptr;
  const float *Afp[4], *Bfp[4];
  if constexpr (!AF) {
    Ag1 = A16 + (size_t)(m0 + (ch1 >> 2)) * K + (ch1 & 3) * 8;
    Ag2 = A16 + (size_t)(m0 + (ch2 >> 2)) * K + (ch2 & 3) * 8;
  } else {
#pragma unroll
    for (int i = 0; i < 4; ++i) {
      const int s = tid + 256 * i, row = s >> 3, gp = s & 7;
      Afp[i] = A32 + (size_t)(m0 + row) * K + ((gp ^ (row & 7)) << 2);
    }
  }
  if constexpr (!BF) {
    Bg1 = B16 + (size_t)(n0 + (ch1 >> 2)) * K + (ch1 & 3) * 8;
    Bg2 = B16 + (size_t)(n0 + (ch2 >> 2)) * K + (ch2 & 3) * 8;
  } else {
#pragma unroll
    for (int i = 0; i < 4; ++i) {
      const int s = tid + 256 * i, row = s >> 3, gp = s & 7;
      Bfp[i] = B32 + (size_t)(n0 + row) * K + ((gp ^ (row & 7)) << 2);
    }
  }

  f32x4 acc[4][4] = {};
#pragma unroll 1
  for (int t = 0; t < 32; ++t) {
    const int k0 = t * 32;
    if constexpr (!AF) {
      cp16(Ag1 + k0, &lA16[ch1 * 8]);
      cp16(Ag2 + k0, &lA16[ch2 * 8]);
    } else {
#pragma unroll
      for (int i = 0; i < 4; ++i) cp16(Afp[i] + k0, &lA32[(tid + 256 * i) * 4]);
    }
    if constexpr (!BF) {
      cp16(Bg1 + k0, &lB16[ch1 * 8]);
      cp16(Bg2 + k0, &lB16[ch2 * 8]);
    } else {
#pragma unroll
      for (int i = 0; i < 4; ++i) cp16(Bfp[i] + k0, &lB32[(tid + 256 * i) * 4]);
    }
    __syncthreads();  // drains vmcnt: staged data visible

    bf16x8 afr[4], bfr[4];
    if constexpr (!AF) {
#pragma unroll
      for (int mi = 0; mi < 4; ++mi)
        afr[mi] = *(const bf16x8*)&lA16[(wr + mi * 16 + lr) * 32 + quad * 8];
    } else {
#pragma unroll
      for (int mi = 0; mi < 4; ++mi) {
        const int row = wr + mi * 16 + lr;
        const int g1 = (2 * quad) ^ (row & 7);       // logical granule 2q
        const f32x4 x0 = *(const f32x4*)&lA32[row * 32 + g1 * 4];
        const f32x4 x1 = *(const f32x4*)&lA32[row * 32 + (g1 ^ 1) * 4];
#pragma unroll
        for (int j = 0; j < 4; ++j) {
          afr[mi][j] = (__bf16)x0[j];
          afr[mi][j + 4] = (__bf16)x1[j];
        }
      }
    }
    if constexpr (!BF) {
#pragma unroll
      for (int ni = 0; ni < 4; ++ni)
        bfr[ni] = *(const bf16x8*)&lB16[(wc + ni * 16 + lr) * 32 + quad * 8];
    } else {
#pragma unroll
      for (int ni = 0; ni < 4; ++ni) {
        const int row = wc + ni * 16 + lr;
        const int g1 = (2 * quad) ^ (row & 7);
        const f32x4 x0 = *(const f32x4*)&lB32[row * 32 + g1 * 4];
        const f32x4 x1 = *(const f32x4*)&lB32[row * 32 + (g1 ^ 1) * 4];
#pragma unroll
        for (int j = 0; j < 4; ++j) {
          bfr[ni][j] = (__bf16)x0[j];
          bfr[ni][j + 4] = (__bf16)x1[j];
        }
      }
    }
#pragma unroll
    for (int mi = 0; mi < 4; ++mi)
#pragma unroll
      for (int ni = 0; ni < 4; ++ni)
        acc[mi][ni] = __builtin_amdgcn_mfma_f32_16x16x32_bf16(
            afr[mi], bfr[ni], acc[mi][ni], 0, 0, 0);
    __syncthreads();
  }

  // Epilogue. C/D frag layout: row = quad*4+r, col = lr.
#pragma unroll
  for (int mi = 0; mi < 4; ++mi)
#pragma unroll
    for (int r = 0; r < 4; ++r) {
      const int row = m0 + wr + mi * 16 + quad * 4 + r;
      if constexpr (!CF) {
        u16* dst = (u16*)Cv + (size_t)row * N + n0 + wc + lr;
#pragma unroll
        for (int ni = 0; ni < 4; ++ni) dst[ni * 16] = f2bf(acc[mi][ni][r]);
      } else {
        float* dst = (float*)Cv + (size_t)row * N + n0 + wc + lr;
#pragma unroll
        for (int ni = 0; ni < 4; ++ni) dst[ni * 16] = acc[mi][ni][r];
      }
    }
}

// One wave per (b, h, window). 64q x 64k x dk=64, bf16. LDS = P only (9.2 KB).
__global__ __launch_bounds__(64) void attn_win_kernel(
    const u16* __restrict__ Xq, const u16* __restrict__ Xk, const u16* __restrict__ Xv,
    u16* __restrict__ Xo) {
  __shared__ u16 P[64 * 72];  // [qp][kp], stride 72 keeps 16B row alignment
  const int bx = blockIdx.x;  // 0..4095
  const int wi = bx & 63, h = (bx >> 6) & 15, b = bx >> 10;
  const int lane = threadIdx.x & 63, quad = lane >> 4, lr = lane & 15;
  const size_t tb = (size_t)b * 4096 + wi * 64;  // window = 64 contiguous tokens
  const u16* qb = Xq + tb * 1024 + h * 64;
  const u16* kb = Xk + tb * 1024 + h * 64;
  const u16* vb = Xv + tb * 1024 + h * 64;

  // S = Q K^T: A-frag Q[m=lr+16mi][k=quad*8+j+32ks]; B-frag K[n=lr+16ni][k]
  bf16x8 aq[4][2], bk[4][2];
#pragma unroll
  for (int mi = 0; mi < 4; ++mi)
#pragma unroll
    for (int ks = 0; ks < 2; ++ks) {
      aq[mi][ks] = *(const bf16x8*)(qb + (size_t)(mi * 16 + lr) * 1024 + ks * 32 + quad * 8);
      bk[mi][ks] = *(const bf16x8*)(kb + (size_t)(mi * 16 + lr) * 1024 + ks * 32 + quad * 8);
    }
  f32x4 s[4][4];
#pragma unroll
  for (int mi = 0; mi < 4; ++mi)
#pragma unroll
    for (int ni = 0; ni < 4; ++ni) {
      f32x4 z = {0.f, 0.f, 0.f, 0.f};
      z = __builtin_amdgcn_mfma_f32_16x16x32_bf16(aq[mi][0], bk[ni][0], z, 0, 0, 0);
      s[mi][ni] = __builtin_amdgcn_mfma_f32_16x16x32_bf16(aq[mi][1], bk[ni][1], z, 0, 0, 0);
    }

  // V B-frags from global, overlapping the softmax latency:
  u16x8 bvr[2][4];
#pragma unroll
  for (int ks = 0; ks < 2; ++ks)
#pragma unroll
    for (int ci = 0; ci < 4; ++ci) {
      const u16* vc = vb + (size_t)(ks * 32 + quad * 8) * 1024 + ci * 16 + lr;
#pragma unroll
      for (int j = 0; j < 8; ++j) bvr[ks][ci][j] = vc[(size_t)j * 1024];
    }

  // softmax: row (quad*4+r of tile mi) spans this quad's 16 lanes x 4 ni regs
  const float sc = 0.125f;  // 1/sqrt(64)
#pragma unroll
  for (int mi = 0; mi < 4; ++mi)
#pragma unroll
    for (int r = 0; r < 4; ++r) {
      float mx = fmaxf(fmaxf(s[mi][0][r], s[mi][1][r]), fmaxf(s[mi][2][r], s[mi][3][r]));
#pragma unroll
      for (int m = 1; m < 16; m <<= 1) mx = fmaxf(mx, __shfl_xor(mx, m));
      float sum = 0.f;
#pragma unroll
      for (int ni = 0; ni < 4; ++ni) {
        float p = __expf((s[mi][ni][r] - mx) * sc);
        s[mi][ni][r] = p;
        sum += p;
      }
#pragma unroll
      for (int m = 1; m < 16; m <<= 1) sum += __shfl_xor(sum, m);
      const float inv = 1.f / sum;
#pragma unroll
      for (int ni = 0; ni < 4; ++ni) s[mi][ni][r] *= inv;
    }

  // P (C/D layout) -> LDS row-major
#pragma unroll
  for (int mi = 0; mi < 4; ++mi)
#pragma unroll
    for (int ni = 0; ni < 4; ++ni)
#pragma unroll
      for (int r = 0; r < 4; ++r)
        P[(mi * 16 + quad * 4 + r) * 72 + ni * 16 + lr] = f2bf(s[mi][ni][r]);
  __syncthreads();  // single wave: compiles to lgkmcnt drain

  // O = P V
  f32x4 o[4][4] = {};
#pragma unroll
  for (int ks = 0; ks < 2; ++ks) {
    bf16x8 ap[4];
#pragma unroll
    for (int mi = 0; mi < 4; ++mi)
      ap[mi] = *(const bf16x8*)&P[(mi * 16 + lr) * 72 + ks * 32 + quad * 8];
#pragma unroll
    for (int mi = 0; mi < 4; ++mi)
#pragma unroll
      for (int ci = 0; ci < 4; ++ci)
        o[mi][ci] = __builtin_amdgcn_mfma_f32_16x16x32_bf16(
            ap[mi], __builtin_bit_cast(bf16x8, bvr[ks][ci]), o[mi][ci], 0, 0, 0);
  }

  // reference permutation: out token = qp*64 + wi
#pragma unroll
  for (int mi = 0; mi < 4; ++mi)
#pragma unroll
    for (int r = 0; r < 4; ++r) {
      const int qp = mi * 16 + quad * 4 + r;
      u16* dst = Xo + ((size_t)b * 4096 + (size_t)qp * 64 + wi) * 1024 + h * 64 + lr;
#pragma unroll
      for (int ci = 0; ci < 4; ++ci) dst[ci * 16] = f2bf(o[mi][ci][r]);
    }
}

extern "C" void kernel_launch(void* const* d_in, const int* in_sizes, int n_in,
                              void* d_out, int out_size, void* d_ws, size_t ws_size,
                              hipStream_t stream) {
  (void)in_sizes; (void)n_in; (void)out_size; (void)ws_size;
  const float* q  = (const float*)d_in[0];
  const float* k  = (const float*)d_in[1];
  const float* v  = (const float*)d_in[2];
  const float* Wq = (const float*)d_in[3];
  const float* Wk = (const float*)d_in[4];
  const float* Wv = (const float*)d_in[5];
  const float* Wo = (const float*)d_in[6];

  constexpr size_t ELEMS = (size_t)16384 * 1024;
  u16* Xq  = (u16*)d_out;          // d_out lower half (bf16)
  u16* Wb3 = (u16*)d_out + ELEMS;  // d_out upper half: Wq/Wk/Wv bf16 (6.3 MB)
  u16* Xk  = (u16*)d_ws;
  u16* Xv  = Xk + ELEMS;
  u16* Xo  = Xv + ELEMS;

  cvtw3_kernel<<<dim3(512, 1, 3), 256, 0, stream>>>(Wq, Wk, Wv, Wb3);
  gemm_m_kernel<1, 0, 0><<<1024, 256, 0, stream>>>(q, Wb3,           Xq);
  gemm_m_kernel<1, 0, 0><<<1024, 256, 0, stream>>>(k, Wb3 + 1048576, Xk);
  gemm_m_kernel<1, 0, 0><<<1024, 256, 0, stream>>>(v, Wb3 + 2097152, Xv);
  attn_win_kernel<<<dim3(4096), 64, 0, stream>>>(Xq, Xk, Xv, Xo);
  gemm_m_kernel<0, 1, 1><<<1024, 256, 0, stream>>>(Xo, Wo, (float*)d_out);
}

// Round 6
// 425.474 us; speedup vs baseline: 1.1581x; 1.1581x over previous
//
#include <hip/hip_runtime.h>

// WindowMultiHeadAttention: b=4, n=4096, d=1024, H=16, dk=64, WIN=64, nw=64.
// R6 = R4/R5 resubmitted (both benches died on container acquisition: infra,
// not kernel — no compile error / no passed:false). One defensive change:
// Wb moved back to d_in[0] (q's buffer), the exact location R0 and R1 both
// PASSED with. Rationale unchanged:
// GEMM + attn are the R0-proven versions VERBATIM (48.5us/GEMM; R2/R3 proved
// cvt-fusion poisons the latency-critical 2-barrier loop).
// Launch graph restructured 9 -> 5 launches with zero-tail grids:
//   1. cvt3   (grid 8192x1x3): q,k,v fp32 -> bf16 into ws slots
//   2. cvtw   (grid 512x1x4):  Wq,Wk,Wv,Wo -> bf16 Wb (q-input buffer,
//                              written AFTER cvt3 fully read q)
//   3. gemmQKV(grid 1024x1x3): batched three projections, one dispatch
//                              (3072 blocks = 6 full 512-block waves, no tail)
//   4. attn   (grid 4096x64thr)
//   5. gemmO  (grid 1024)
//
// Buffer plan (lifetimes verified):
//   ws slot0/1/2 (3x32MB=100.66MB): qb/kb/vb; slot0 reused for Xo after attn
//   q input buf : Wb (bf16 weights, 8.4MB) - written AFTER cvt3 read q
//                 (R0/R1-proven location); gemm_o reads it while writing
//                 d_out (disjoint buffers) -> safe
//   d_out.lo    : Xq (bf16) -> dead after attn, clobbered by final fp32 C
//   d_out.hi    : Xk (bf16) -> dead after attn, clobbered by final fp32 C
//   v input buf : Xv (bf16, 33.5MB of 67) - written after cvt3 read v
//   k input buf : never written

typedef unsigned short u16;
typedef unsigned int u32;
typedef __bf16 bf16x8 __attribute__((ext_vector_type(8)));
typedef float f32x4 __attribute__((ext_vector_type(4)));
typedef u16 u16x8 __attribute__((ext_vector_type(8)));

__device__ __forceinline__ u16 f2bf(float f) {
  u32 u = __builtin_bit_cast(u32, f);
  u += 0x7fffu + ((u >> 16) & 1u);  // RNE
  return (u16)(u >> 16);
}

__device__ __forceinline__ void cvt8_store(const float* __restrict__ src,
                                           u16* __restrict__ dst, size_t i) {
  const float4 a = *(const float4*)(src + i);
  const float4 b = *(const float4*)(src + i + 4);
  u16x8 r;
  r[0] = f2bf(a.x); r[1] = f2bf(a.y); r[2] = f2bf(a.z); r[3] = f2bf(a.w);
  r[4] = f2bf(b.x); r[5] = f2bf(b.y); r[6] = f2bf(b.z); r[7] = f2bf(b.w);
  *(u16x8*)(dst + i) = r;
}

// q,k,v (16.78M elems each) -> bf16, z selects tensor; dst = ws + z*ELEMS.
__global__ __launch_bounds__(256) void cvt3_kernel(
    const float* __restrict__ q, const float* __restrict__ k,
    const float* __restrict__ v, u16* __restrict__ dst) {
  const float* src = (blockIdx.z == 0) ? q : (blockIdx.z == 1) ? k : v;
  cvt8_store(src, dst + (size_t)blockIdx.z * 16777216,
             ((size_t)blockIdx.x * 256 + threadIdx.x) * 8);
}

__global__ __launch_bounds__(256) void cvtw_kernel(
    const float* __restrict__ Wq, const float* __restrict__ Wk,
    const float* __restrict__ Wv, const float* __restrict__ Wo,
    u16* __restrict__ dst) {
  const float* src = (blockIdx.z == 0) ? Wq : (blockIdx.z == 1) ? Wk
                   : (blockIdx.z == 2) ? Wv : Wo;
  cvt8_store(src, dst + (size_t)blockIdx.z * 1048576,
             ((size_t)blockIdx.x * 256 + threadIdx.x) * 8);
}

__device__ __forceinline__ void cp16(const u16* g, u16* l) {
  // async global->LDS, 16B/lane; LDS dst = wave-uniform base + lane*16.
  __builtin_amdgcn_global_load_lds((const __attribute__((address_space(1))) void*)g,
                                   (__attribute__((address_space(3))) void*)l, 16, 0, 0);
}

// C[M,N] = A[M,K]*B[N,K]^T, bf16 in, fp32 acc. M=16384, N=K=1024.
// 128x128 tile, BK=32, 4 waves 2x2. XCD-aware swizzle: with round-robin
// block->XCD (x%8), XCD x owns m-tiles [x*16, x*16+16), n fastest ->
// per-XCD L2 working set ~4MB (R0-proven: FETCH 26.5MB, 48.5us).
// Body is R0's gemm_bt_kernel verbatim, factored for reuse by both wrappers.
__device__ __forceinline__ void gemm_core(const u16* __restrict__ A,
                                          const u16* __restrict__ B,
                                          void* __restrict__ Cv, int cf) {
  constexpr int N = 1024, K = 1024;
  __shared__ u16 lA[128 * 32];
  __shared__ u16 lB[128 * 32];
  const int tid = threadIdx.x;
  const int lane = tid & 63, w = tid >> 6;
  const int quad = lane >> 4, lr = lane & 15;
  const int lid = blockIdx.x;          // 0..1023 per z-slice
  const int xcd = lid & 7, slot = lid >> 3;
  const int m0 = (xcd * 16 + (slot >> 3)) * 128;
  const int n0 = (slot & 7) * 128;
  const int wr = (w >> 1) * 64, wc = (w & 1) * 64;

  const int ch1 = tid, ch2 = tid + 256;  // 512 x 16B chunks per 128x32 tile
  const u16* Ag1 = A + (size_t)(m0 + (ch1 >> 2)) * K + (ch1 & 3) * 8;
  const u16* Ag2 = A + (size_t)(m0 + (ch2 >> 2)) * K + (ch2 & 3) * 8;
  const u16* Bg1 = B + (size_t)(n0 + (ch1 >> 2)) * K + (ch1 & 3) * 8;
  const u16* Bg2 = B + (size_t)(n0 + (ch2 >> 2)) * K + (ch2 & 3) * 8;

  f32x4 acc[4][4] = {};
  for (int k0 = 0; k0 < K; k0 += 32) {
    cp16(Ag1 + k0, &lA[ch1 * 8]);
    cp16(Ag2 + k0, &lA[ch2 * 8]);
    cp16(Bg1 + k0, &lB[ch1 * 8]);
    cp16(Bg2 + k0, &lB[ch2 * 8]);
    __syncthreads();  // drains vmcnt(0): staged data visible
    bf16x8 afr[4], bfr[4];
#pragma unroll
    for (int mi = 0; mi < 4; ++mi)
      afr[mi] = *(const bf16x8*)&lA[(wr + mi * 16 + lr) * 32 + quad * 8];
#pragma unroll
    for (int ni = 0; ni < 4; ++ni)
      bfr[ni] = *(const bf16x8*)&lB[(wc + ni * 16 + lr) * 32 + quad * 8];
#pragma unroll
    for (int mi = 0; mi < 4; ++mi)
#pragma unroll
      for (int ni = 0; ni < 4; ++ni)
        acc[mi][ni] = __builtin_amdgcn_mfma_f32_16x16x32_bf16(afr[mi], bfr[ni], acc[mi][ni], 0, 0, 0);
    __syncthreads();
  }
  // C/D layout per 16x16 tile: row = quad*4+r, col = lr
#pragma unroll
  for (int mi = 0; mi < 4; ++mi)
#pragma unroll
    for (int r = 0; r < 4; ++r) {
      const int row = m0 + wr + mi * 16 + quad * 4 + r;
      if (!cf) {
        u16* dst = (u16*)Cv + (size_t)row * N + n0 + wc + lr;
#pragma unroll
        for (int ni = 0; ni < 4; ++ni) dst[ni * 16] = f2bf(acc[mi][ni][r]);
      } else {
        float* dst = (float*)Cv + (size_t)row * N + n0 + wc + lr;
#pragma unroll
        for (int ni = 0; ni < 4; ++ni) dst[ni * 16] = acc[mi][ni][r];
      }
    }
}

// Batched Q/K/V projection: z selects A (ws slot), B (Wb+z*1M), C.
__global__ __launch_bounds__(256, 2) void gemm_qkv_kernel(
    const u16* __restrict__ ws, const u16* __restrict__ Wb,
    u16* __restrict__ Xq, u16* __restrict__ Xk, u16* __restrict__ Xv) {
  const int z = blockIdx.z;
  const u16* A = ws + (size_t)z * 16777216;
  const u16* B = Wb + (size_t)z * 1048576;
  u16* C = (z == 0) ? Xq : (z == 1) ? Xk : Xv;
  gemm_core(A, B, C, 0);
}

__global__ __launch_bounds__(256, 2) void gemm_o_kernel(
    const u16* __restrict__ A, const u16* __restrict__ B,
    float* __restrict__ C) {
  gemm_core(A, B, C, 1);
}

// One wave per (b, h, window). 64q x 64k x dk=64, bf16. LDS = P only (9.2 KB)
// -> 16 blocks/CU. V B-frags read directly from global (L2-resident).
__global__ __launch_bounds__(64) void attn_win_kernel(
    const u16* __restrict__ Xq, const u16* __restrict__ Xk, const u16* __restrict__ Xv,
    u16* __restrict__ Xo) {
  __shared__ u16 P[64 * 72];  // [qp][kp], stride 72 keeps 16B row alignment
  const int bx = blockIdx.x;  // 0..4095
  const int wi = bx & 63, h = (bx >> 6) & 15, b = bx >> 10;
  const int lane = threadIdx.x & 63, quad = lane >> 4, lr = lane & 15;
  const size_t tb = (size_t)b * 4096 + wi * 64;  // window = 64 contiguous tokens
  const u16* qb = Xq + tb * 1024 + h * 64;
  const u16* kb = Xk + tb * 1024 + h * 64;
  const u16* vb = Xv + tb * 1024 + h * 64;

  // S = Q K^T: A-frag Q[m=lr+16mi][k=quad*8+j+32ks]; B-frag K[n=lr+16ni][k]
  bf16x8 aq[4][2], bk[4][2];
#pragma unroll
  for (int mi = 0; mi < 4; ++mi)
#pragma unroll
    for (int ks = 0; ks < 2; ++ks) {
      aq[mi][ks] = *(const bf16x8*)(qb + (size_t)(mi * 16 + lr) * 1024 + ks * 32 + quad * 8);
      bk[mi][ks] = *(const bf16x8*)(kb + (size_t)(mi * 16 + lr) * 1024 + ks * 32 + quad * 8);
    }
  f32x4 s[4][4];
#pragma unroll
  for (int mi = 0; mi < 4; ++mi)
#pragma unroll
    for (int ni = 0; ni < 4; ++ni) {
      f32x4 z = {0.f, 0.f, 0.f, 0.f};
      z = __builtin_amdgcn_mfma_f32_16x16x32_bf16(aq[mi][0], bk[ni][0], z, 0, 0, 0);
      s[mi][ni] = __builtin_amdgcn_mfma_f32_16x16x32_bf16(aq[mi][1], bk[ni][1], z, 0, 0, 0);
    }

  // V B-frags from global, overlapping the softmax latency:
  u16x8 bvr[2][4];
#pragma unroll
  for (int ks = 0; ks < 2; ++ks)
#pragma unroll
    for (int ci = 0; ci < 4; ++ci) {
      const u16* vc = vb + (size_t)(ks * 32 + quad * 8) * 1024 + ci * 16 + lr;
#pragma unroll
      for (int j = 0; j < 8; ++j) bvr[ks][ci][j] = vc[(size_t)j * 1024];
    }

  // softmax: row (quad*4+r of tile mi) spans this quad's 16 lanes x 4 ni regs
  const float sc = 0.125f;  // 1/sqrt(64)
#pragma unroll
  for (int mi = 0; mi < 4; ++mi)
#pragma unroll
    for (int r = 0; r < 4; ++r) {
      float mx = fmaxf(fmaxf(s[mi][0][r], s[mi][1][r]), fmaxf(s[mi][2][r], s[mi][3][r]));
#pragma unroll
      for (int m = 1; m < 16; m <<= 1) mx = fmaxf(mx, __shfl_xor(mx, m));
      float sum = 0.f;
#pragma unroll
      for (int ni = 0; ni < 4; ++ni) {
        float p = __expf((s[mi][ni][r] - mx) * sc);
        s[mi][ni][r] = p;
        sum += p;
      }
#pragma unroll
      for (int m = 1; m < 16; m <<= 1) sum += __shfl_xor(sum, m);
      const float inv = 1.f / sum;
#pragma unroll
      for (int ni = 0; ni < 4; ++ni) s[mi][ni][r] *= inv;
    }

  // P (C/D layout) -> LDS row-major
#pragma unroll
  for (int mi = 0; mi < 4; ++mi)
#pragma unroll
    for (int ni = 0; ni < 4; ++ni)
#pragma unroll
      for (int r = 0; r < 4; ++r)
        P[(mi * 16 + quad * 4 + r) * 72 + ni * 16 + lr] = f2bf(s[mi][ni][r]);
  __syncthreads();  // single wave: compiles to lgkmcnt drain

  // O = P V
  f32x4 o[4][4] = {};
#pragma unroll
  for (int ks = 0; ks < 2; ++ks) {
    bf16x8 ap[4];
#pragma unroll
    for (int mi = 0; mi < 4; ++mi)
      ap[mi] = *(const bf16x8*)&P[(mi * 16 + lr) * 72 + ks * 32 + quad * 8];
#pragma unroll
    for (int mi = 0; mi < 4; ++mi)
#pragma unroll
      for (int ci = 0; ci < 4; ++ci)
        o[mi][ci] = __builtin_amdgcn_mfma_f32_16x16x32_bf16(
            ap[mi], __builtin_bit_cast(bf16x8, bvr[ks][ci]), o[mi][ci], 0, 0, 0);
  }

  // reference permutation: out token = qp*64 + wi
#pragma unroll
  for (int mi = 0; mi < 4; ++mi)
#pragma unroll
    for (int r = 0; r < 4; ++r) {
      const int qp = mi * 16 + quad * 4 + r;
      u16* dst = Xo + ((size_t)b * 4096 + (size_t)qp * 64 + wi) * 1024 + h * 64 + lr;
#pragma unroll
      for (int ci = 0; ci < 4; ++ci) dst[ci * 16] = f2bf(o[mi][ci][r]);
    }
}

extern "C" void kernel_launch(void* const* d_in, const int* in_sizes, int n_in,
                              void* d_out, int out_size, void* d_ws, size_t ws_size,
                              hipStream_t stream) {
  (void)in_sizes; (void)n_in; (void)out_size; (void)ws_size;
  const float* q  = (const float*)d_in[0];
  const float* k  = (const float*)d_in[1];
  const float* v  = (const float*)d_in[2];
  const float* Wq = (const float*)d_in[3];
  const float* Wk = (const float*)d_in[4];
  const float* Wv = (const float*)d_in[5];
  const float* Wo = (const float*)d_in[6];

  constexpr size_t ELEMS = (size_t)16384 * 1024;
  u16* qkvb = (u16*)d_ws;              // slot0 qb / slot1 kb / slot2 vb
  u16* Xo   = (u16*)d_ws;              // slot0 reused after attn (qb dead)
  u16* Wb   = (u16*)d_in[0];           // bf16 weights in q's buffer (q consumed
                                       // by cvt3 first) -- R0/R1-proven spot
  u16* Xq   = (u16*)d_out;             // d_out lower half
  u16* Xk   = (u16*)d_out + ELEMS;     // d_out upper half
  u16* Xv   = (u16*)d_in[2];           // v's buffer (v consumed by cvt3)

  cvt3_kernel<<<dim3(8192, 1, 3), 256, 0, stream>>>(q, k, v, qkvb);
  cvtw_kernel<<<dim3(512, 1, 4), 256, 0, stream>>>(Wq, Wk, Wv, Wo, Wb);
  gemm_qkv_kernel<<<dim3(1024, 1, 3), 256, 0, stream>>>(qkvb, Wb, Xq, Xk, Xv);
  attn_win_kernel<<<dim3(4096), 64, 0, stream>>>(Xq, Xk, Xv, Xo);
  gemm_o_kernel<<<dim3(1024), 256, 0, stream>>>(Xo, Wb + 3145728, (float*)d_out);
}